// Round 21
// baseline (4288.158 us; speedup 1.0000x reference)
//
#include <hip/hip_runtime.h>
#include <hip/hip_bf16.h>
#include <hip/hip_fp16.h>

#define B_   32
#define TIN  16
#define X_   8192
#define H_   64
#define F_   128
#define K_   5
#define DEPTH 3
#define TOUT 32
#define TILE 256          // 4 waves x 64 x-columns (4 col-groups each)
#define PROW (X_ + 4)     // padded rows per batch: 2 zero | X | 2 zero

typedef __attribute__((ext_vector_type(8))) _Float16 h16x8;
typedef __attribute__((ext_vector_type(4))) _Float16 h16x4;
typedef __attribute__((ext_vector_type(2))) _Float16 h16x2;
typedef __attribute__((ext_vector_type(2))) __fp16 fp16x2;
typedef __attribute__((ext_vector_type(4))) float f32x4;

// GELU via A&S 7.1.25 3-term erf (fp32, used in decoder head only)
__device__ __forceinline__ float gelu_fast(float z) {
    float t = fminf(fabsf(z) * 0.70710678118654752f, 3.9192f);
    float w = __builtin_amdgcn_rcpf(__builtin_fmaf(0.47047f, t, 1.0f));
    float p = w * __builtin_fmaf(w, __builtin_fmaf(w, 0.7478556f, -0.0958798f), 0.3480242f);
    float e = __expf(-t * t);
    float erf_abs = __builtin_fmaf(-p, e, 1.0f);
    return 0.5f * z * (1.0f + copysignf(erf_abs, z));
}

// packed-fp16 GELU: f32x4 -> h16x4 via cvt_pkrtz + __half2 A&S 7.1.25
__device__ __forceinline__ h16x4 gelu4(f32x4 v) {
    union HU { __half2 h; h16x2 v; fp16x2 f; unsigned u; };
    const __half2 k1  = __float2half2_rn(1.0f);
    const __half2 kP  = __float2half2_rn(0.47047f);
    const __half2 kA1 = __float2half2_rn(0.3480242f);
    const __half2 kA2 = __float2half2_rn(-0.0958798f);
    const __half2 kA3 = __float2half2_rn(0.7478556f);
    const __half2 kH  = __float2half2_rn(0.5f);
    const __half2 kC  = __float2half2_rn(0.70710678f);
    h16x4 out;
    #pragma unroll
    for (int p2 = 0; p2 < 2; ++p2) {
        HU z; z.f = __builtin_amdgcn_cvt_pkrtz(v[p2 * 2], v[p2 * 2 + 1]);
        HU az; az.u = z.u & 0x7FFF7FFFu;                      // |z|
        __half2 t = __hmul2(az.h, kC);
        __half2 w = h2rcp(__hfma2(kP, t, k1));
        __half2 p = __hmul2(w, __hfma2(w, __hfma2(w, kA3, kA2), kA1));
        __half2 e = h2exp(__hneg2(__hmul2(t, t)));
        HU erf; erf.h = __hfma2(__hneg2(p), e, k1);           // 1 - p*e  (>= 0)
        HU erfs; erfs.u = erf.u | (z.u & 0x80008000u);        // copysign(erf, z)
        __half2 g = __hmul2(z.h, __hfma2(kH, erfs.h, kH));    // z*(0.5+0.5*erf)
        HU go; go.h = g;
        out[p2 * 2]     = go.v[0];
        out[p2 * 2 + 1] = go.v[1];
    }
    return out;
}

// packed f32x4 -> h16x4 (RTZ)
__device__ __forceinline__ h16x4 cvt4(f32x4 v) {
    union CU { fp16x2 f; h16x2 v; };
    CU lo, hi;
    lo.f = __builtin_amdgcn_cvt_pkrtz(v[0], v[1]);
    hi.f = __builtin_amdgcn_cvt_pkrtz(v[2], v[3]);
    h16x4 r;
    r[0] = lo.v[0]; r[1] = lo.v[1]; r[2] = hi.v[0]; r[3] = hi.v[1];
    return r;
}

// swizzled LDS address: row stride rb bytes, XOR (row&7)<<4 spreads banks
__device__ __forceinline__ char* lp(void* base, int row, int cb, int rb) {
    return (char*)base + row * rb + (cb ^ ((row & 7) << 4));
}
// 16x32 activation fragment from swizzled LDS (B role): lane -> (x=row, d=kt*32+l4*8+e)
__device__ __forceinline__ h16x8 lda(const void* base, int row, int kt, int rb, int lane) {
    return *(const h16x8*)((const char*)base + row * rb +
                           ((kt * 64 + ((lane >> 4) << 4)) ^ ((row & 7) << 4)));
}
// packed weight fragments: contiguous per fragment, fully coalesced wave reads
__device__ __forceinline__ h16x4 ldp16(const _Float16* w, int frag, int lane) {
    return *(const h16x4*)&w[(frag << 8) + (lane << 2)];
}
__device__ __forceinline__ h16x8 ldp32(const _Float16* w, int frag, int lane) {
    return *(const h16x8*)&w[(frag << 9) + (lane << 3)];
}

__device__ __forceinline__ f32x4 mfma32(h16x8 a, h16x8 b, f32x4 c) {
    return __builtin_amdgcn_mfma_f32_16x16x32_f16(a, b, c, 0, 0, 0);
}
__device__ __forceinline__ f32x4 mfma16(h16x4 a, h16x4 b, f32x4 c) {
    return __builtin_amdgcn_mfma_f32_16x16x16f16(a, b, c, 0, 0, 0);
}

// ---------------- weight prep: fp32 -> packed fp16 fragments ----------------
__global__ __launch_bounds__(256) void k_prep_conv(const float* __restrict__ s,
                                                   _Float16* __restrict__ w) {
    int t = blockIdx.x * 256 + threadIdx.x;
    if (t >= DEPTH * 20480) return;
    int i = t / 20480, r = t % 20480;
    int frag = r >> 9, lane = (r >> 3) & 63, e = r & 7;
    int k = frag >> 3, kt = (frag >> 2) & 1, nt = frag & 3;
    int o = nt * 16 + (lane & 15);
    int d = kt * 32 + ((lane >> 4) << 3) + e;
    w[t] = (_Float16)s[((i * 64 + o) * 64 + d) * 5 + k];
}
__global__ __launch_bounds__(256) void k_pack16(const float* __restrict__ s,
                                                _Float16* __restrict__ w,
                                                int NT, int KT, int K, int total) {
    int t = blockIdx.x * 256 + threadIdx.x;
    if (t >= total) return;
    int per = NT * KT * 256;
    int li = t / per, r = t % per;
    int frag = r >> 8, lane = (r >> 2) & 63, e = r & 3;
    int kt = frag / NT, nt = frag % NT;
    int n = nt * 16 + (lane & 15);
    int kk = kt * 16 + ((lane >> 4) << 2) + e;
    w[t] = (_Float16)s[li * (NT * 16 * K) + n * K + kk];
}

// zero the halo pad rows of both psi buffers (rows 0,1 and X+2,X+3 per batch)
__global__ __launch_bounds__(256) void k_zero_pads(_Float16* __restrict__ pA,
                                                   _Float16* __restrict__ pB) {
    int i = blockIdx.x * 256 + threadIdx.x;      // over B*4*64
    if (i >= B_ * 4 * 64) return;
    int b = i >> 8, r = (i >> 6) & 3, h = i & 63;
    int row = (r < 2) ? r : (X_ + r);            // 0,1,X+2,X+3
    size_t off = ((size_t)b * PROW + row) * H_ + h;
    pA[off] = (_Float16)0.f;
    pB[off] = (_Float16)0.f;
}

// ---------------- encoder (runs once; fp32 VALU, writes fp16 padded psi) ----------------
__global__ __launch_bounds__(256) void k_encoder(const float* __restrict__ xin,
                                                 const float* __restrict__ enc_w,
                                                 const float* __restrict__ enc_b,
                                                 _Float16* __restrict__ psi) {
    const int b  = blockIdx.y;
    const int x0 = blockIdx.x * 64;
    __shared__ float s_x[TIN][64];
    __shared__ float s_w[TIN][H_];
    __shared__ float s_p[64][H_];
    const int tid = threadIdx.x;

    for (int idx = tid; idx < TIN * 64; idx += 256) {
        int t = idx >> 6, xl = idx & 63;
        s_x[t][xl] = xin[((size_t)b * TIN + t) * X_ + x0 + xl];
    }
    for (int idx = tid; idx < TIN * H_; idx += 256) {
        int t = idx >> 6, h = idx & 63;
        s_w[t][h] = enc_w[h * TIN + t];
    }
    __syncthreads();
    {
        int h = tid & 63, grp = tid >> 6;
        float bias = enc_b[h];
        for (int r = 0; r < 16; ++r) {
            int xl = grp * 16 + r;
            float acc = bias;
            #pragma unroll
            for (int t = 0; t < TIN; ++t) acc += s_x[t][xl] * s_w[t][h];
            s_p[xl][h] = acc;
        }
    }
    __syncthreads();
    {
        int lane = tid & 63, wv = tid >> 6;
        for (int r = 0; r < 16; ++r) {
            int xl = wv * 16 + r;
            float v = s_p[xl][lane];
            float s = v;
            #pragma unroll
            for (int off = 32; off; off >>= 1) s += __shfl_xor(s, off);
            float mu = s * (1.0f / 64.0f);
            float dv = v - mu;
            float q = dv * dv;
            #pragma unroll
            for (int off = 32; off; off >>= 1) q += __shfl_xor(q, off);
            float sd = sqrtf(q * (1.0f / 63.0f)) + 1e-6f;
            psi[((size_t)b * PROW + 2 + x0 + xl) * H_ + lane] = (_Float16)(dv / sd);
        }
    }
}

// ---------------- fused layer: M=64/wave, register chain, zero-barrier tail ----------------
// psi fp16 padded [b][2|X|2][64]. TILE=256, 4 waves x 64 cols (4 cgs).
// Residual read from sA. LN writes into separate sB (wave-private rows) and
// full-line copy-out reads sB -> NO second barrier. launch_bounds (256,2):
// 2 blocks/CU (LDS 66KB x2 = 132KB <= 160KB) keeps streaming footprint
// <= ~128 KB/CU L2 share. gelu + conv-out cvt in packed fp16.
__global__ __launch_bounds__(256, 2) void k_layer(const _Float16* __restrict__ pin,
                                                  _Float16* __restrict__ pout,
                                                  const _Float16* __restrict__ cw,
                                                  const float* __restrict__ cb,
                                                  const _Float16* __restrict__ w1,
                                                  const float* __restrict__ b1,
                                                  const _Float16* __restrict__ w2,
                                                  const float* __restrict__ b2,
                                                  const float* __restrict__ g,
                                                  const float* __restrict__ bt,
                                                  const _Float16* __restrict__ d1,
                                                  const float* __restrict__ b1d,
                                                  const float* __restrict__ w2d,
                                                  const float* __restrict__ b2d,
                                                  float* __restrict__ yout, int step) {
    __shared__ __align__(16) _Float16 sA[(TILE + 4) * 64];   // 260 rows x 128B = 33.3 KB
    __shared__ __align__(16) _Float16 sB[TILE * 64];         // 256 rows x 128B = 32.0 KB

    const int tid  = threadIdx.x;
    const int b    = blockIdx.y;
    const int x0   = blockIdx.x * TILE;
    const int lane = tid & 63, wv = tid >> 6;
    const int l15  = lane & 15, l4 = lane >> 4;
    const int XW   = wv * 64;                 // wave owns 64 x-columns
    const int xg0  = x0 + XW + l15;

    // ---- stage psi rows: padded rows [x0, x0+260) = global x [x0-2, x0+258)
    {
        const _Float16* src = pin + ((size_t)b * PROW + x0) * H_;
        for (int idx = tid; idx < (TILE + 4) * 8; idx += 256) {
            int r = idx >> 3, c8 = idx & 7;
            h16x8 v = *(const h16x8*)(src + r * H_ + c8 * 8);
            *(h16x8*)lp(sA, r, c8 * 16, 128) = v;
        }
    }
    __syncthreads();   // the ONLY barrier

    // ---- conv (K=32, swapped): acc[cg][nt]; each weight frag feeds 4 cgs
    f32x4 acc[4][4];
    #pragma unroll
    for (int nt = 0; nt < 4; ++nt) {
        f32x4 bb = *(const f32x4*)&cb[nt * 16 + (l4 << 2)];
        #pragma unroll
        for (int cg = 0; cg < 4; ++cg) acc[cg][nt] = bb;
    }
    #pragma unroll
    for (int k = 0; k < K_; ++k) {
        h16x8 bfrag[4][2];
        #pragma unroll
        for (int cg = 0; cg < 4; ++cg) {
            bfrag[cg][0] = lda(sA, XW + cg * 16 + l15 + k, 0, 128, lane);
            bfrag[cg][1] = lda(sA, XW + cg * 16 + l15 + k, 1, 128, lane);
        }
        #pragma unroll
        for (int nt = 0; nt < 4; ++nt) {
            h16x8 a0 = ldp32(cw, (k * 2 + 0) * 4 + nt, lane);
            h16x8 a1 = ldp32(cw, (k * 2 + 1) * 4 + nt, lane);
            #pragma unroll
            for (int cg = 0; cg < 4; ++cg) {
                acc[cg][nt] = mfma32(a0, bfrag[cg][0], acc[cg][nt]);
                acc[cg][nt] = mfma32(a1, bfrag[cg][1], acc[cg][nt]);
            }
        }
    }
    h16x4 hb[4][4];
    #pragma unroll
    for (int cg = 0; cg < 4; ++cg)
        #pragma unroll
        for (int nt = 0; nt < 4; ++nt) hb[cg][nt] = cvt4(acc[cg][nt]);

    // ---- mlp1 (K=16, swapped): m[f][x] = W1 . h ; each frag feeds 4 cgs
    f32x4 m[4][8];
    #pragma unroll
    for (int ft = 0; ft < 8; ++ft) {
        f32x4 bb = *(const f32x4*)&b1[ft * 16 + (l4 << 2)];
        #pragma unroll
        for (int cg = 0; cg < 4; ++cg) m[cg][ft] = bb;
    }
    #pragma unroll
    for (int kt = 0; kt < 4; ++kt) {
        #pragma unroll
        for (int ft = 0; ft < 8; ++ft) {
            h16x4 aw = ldp16(w1, kt * 8 + ft, lane);
            #pragma unroll
            for (int cg = 0; cg < 4; ++cg) m[cg][ft] = mfma16(aw, hb[cg][kt], m[cg][ft]);
        }
    }

    // ---- gelu in packed fp16 (long VALU phase); m dies here
    h16x4 mb[4][8];
    #pragma unroll
    for (int cg = 0; cg < 4; ++cg)
        #pragma unroll
        for (int ft = 0; ft < 8; ++ft) mb[cg][ft] = gelu4(m[cg][ft]);

    // ---- residual from sA (same fp16 values; saves global loads)
    h16x4 res[4][4];
    #pragma unroll
    for (int cg = 0; cg < 4; ++cg) {
        int ri = 2 + XW + cg * 16 + l15;
        #pragma unroll
        for (int nt = 0; nt < 4; ++nt)
            res[cg][nt] = *(const h16x4*)lp(sA, ri, nt * 32 + (l4 << 3), 128);
    }

    // ---- mlp2 (K=16, swapped): o[d][x] = W2 . m ; each frag feeds 4 cgs
    f32x4 o[4][4];
    #pragma unroll
    for (int nt = 0; nt < 4; ++nt) {
        f32x4 bb = *(const f32x4*)&b2[nt * 16 + (l4 << 2)];
        #pragma unroll
        for (int cg = 0; cg < 4; ++cg) o[cg][nt] = bb;
    }
    #pragma unroll
    for (int kt = 0; kt < 8; ++kt) {
        #pragma unroll
        for (int nt = 0; nt < 4; ++nt) {
            h16x4 aw = ldp16(w2, kt * 4 + nt, lane);
            #pragma unroll
            for (int cg = 0; cg < 4; ++cg) o[cg][nt] = mfma16(aw, mb[cg][kt], o[cg][nt]);
        }
    }

    // ---- residual + LN + clip -> ps regs + write into sB (wave-private rows, no barrier)
    h16x4 ps[4][4];
    #pragma unroll
    for (int cg = 0; cg < 4; ++cg) {
        float v[4][4];
        float s = 0.f;
        #pragma unroll
        for (int nt = 0; nt < 4; ++nt) {
            #pragma unroll
            for (int j = 0; j < 4; ++j) {
                v[nt][j] = o[cg][nt][j] + (float)res[cg][nt][j];
                s += v[nt][j];
            }
        }
        s += __shfl_xor(s, 16); s += __shfl_xor(s, 32);
        float mu = s * (1.0f / 64.0f);
        float q = 0.f;
        #pragma unroll
        for (int nt = 0; nt < 4; ++nt) {
            #pragma unroll
            for (int j = 0; j < 4; ++j) { v[nt][j] -= mu; q += v[nt][j] * v[nt][j]; }
        }
        q += __shfl_xor(q, 16); q += __shfl_xor(q, 32);
        float rs = rsqrtf(q * (1.0f / 64.0f) + 1e-5f);
        int ri = XW + cg * 16 + l15;
        #pragma unroll
        for (int nt = 0; nt < 4; ++nt) {
            f32x4 gg = *(const f32x4*)&g[nt * 16 + (l4 << 2)];
            f32x4 bb = *(const f32x4*)&bt[nt * 16 + (l4 << 2)];
            #pragma unroll
            for (int j = 0; j < 4; ++j) {
                float ov = v[nt][j] * rs * gg[j] + bb[j];
                ov = fminf(10.0f, fmaxf(-10.0f, ov));
                ps[cg][nt][j] = (_Float16)ov;
            }
            *(h16x4*)lp(sB, ri, nt * 32 + (l4 << 3), 128) = ps[cg][nt];
        }
    }

    // ---- copy-out from sB: full 128B lines, wave-private rows [XW, XW+64)
    {
        _Float16* dst = pout + ((size_t)b * PROW + 2 + x0 + XW) * H_;
        int lr = lane >> 3, c8 = lane & 7;        // 8 rows x 8 chunks per iter
        #pragma unroll
        for (int it = 0; it < 8; ++it) {
            int r = it * 8 + lr;                  // row within wave slab [0,64)
            h16x8 v = *(const h16x8*)lp(sB, XW + r, c8 * 16, 128);
            *(h16x8*)(dst + r * H_ + c8 * 8) = v;
        }
    }

    // ---- fused decoder head (depth 2 only; fp32 gelu — feeds y directly)
    if (yout) {
        f32x4 dacc[4][4];
        #pragma unroll
        for (int ht = 0; ht < 4; ++ht) {
            f32x4 bb = *(const f32x4*)&b1d[ht * 16 + (l4 << 2)];
            #pragma unroll
            for (int cg = 0; cg < 4; ++cg) dacc[cg][ht] = bb;
        }
        #pragma unroll
        for (int kt = 0; kt < 4; ++kt) {
            #pragma unroll
            for (int ht = 0; ht < 4; ++ht) {
                h16x4 aw = ldp16(d1, kt * 4 + ht, lane);
                #pragma unroll
                for (int cg = 0; cg < 4; ++cg) dacc[cg][ht] = mfma16(aw, ps[cg][kt], dacc[cg][ht]);
            }
        }
        float y[4] = {0.f, 0.f, 0.f, 0.f};
        #pragma unroll
        for (int ht = 0; ht < 4; ++ht) {
            f32x4 wq = *(const f32x4*)&w2d[ht * 16 + (l4 << 2)];
            #pragma unroll
            for (int cg = 0; cg < 4; ++cg) {
                #pragma unroll
                for (int j = 0; j < 4; ++j) y[cg] += gelu_fast(dacc[cg][ht][j]) * wq[j];
            }
        }
        #pragma unroll
        for (int cg = 0; cg < 4; ++cg) {
            y[cg] += __shfl_xor(y[cg], 16);
            y[cg] += __shfl_xor(y[cg], 32);
        }
        if (l4 == 0) {
            size_t ybase = ((size_t)b * TOUT + step) * X_;
            #pragma unroll
            for (int cg = 0; cg < 4; ++cg)
                yout[ybase + xg0 + cg * 16] = y[cg] + b2d[0];
        }
    }
}

extern "C" void kernel_launch(void* const* d_in, const int* in_sizes, int n_in,
                              void* d_out, int out_size, void* d_ws, size_t ws_size,
                              hipStream_t stream) {
    const float* xin    = (const float*)d_in[0];
    const float* enc_w  = (const float*)d_in[1];
    const float* enc_b  = (const float*)d_in[2];
    const float* conv_w = (const float*)d_in[3];
    const float* conv_b = (const float*)d_in[4];
    const float* mlp_w1 = (const float*)d_in[5];
    const float* mlp_b1 = (const float*)d_in[6];
    const float* mlp_w2 = (const float*)d_in[7];
    const float* mlp_b2 = (const float*)d_in[8];
    const float* ln_g   = (const float*)d_in[9];
    const float* ln_b   = (const float*)d_in[10];
    const float* dec_w1 = (const float*)d_in[11];
    const float* dec_b1 = (const float*)d_in[12];
    const float* dec_w2 = (const float*)d_in[13];
    const float* dec_b2 = (const float*)d_in[14];
    float* out = (float*)d_out;

    const size_t PSI = (size_t)B_ * PROW * H_;       // fp16 elements
    _Float16* psiA = (_Float16*)d_ws;
    _Float16* psiB = psiA + PSI;
    _Float16* cwf = psiB + PSI;               // [3][40 frags][512]
    _Float16* w1f = cwf + 61440;              // [3][32 frags][256]
    _Float16* w2f = w1f + 24576;              // [3][32 frags][256]
    _Float16* d1f = w2f + 24576;              // [16 frags][256]
    (void)ws_size; (void)n_in; (void)in_sizes; (void)out_size;

    k_zero_pads<<<32, 256, 0, stream>>>(psiA, psiB);
    k_prep_conv<<<240, 256, 0, stream>>>(conv_w, cwf);
    k_pack16<<<96, 256, 0, stream>>>(mlp_w1, w1f, 8, 4, 64, 24576);
    k_pack16<<<96, 256, 0, stream>>>(mlp_w2, w2f, 4, 8, 128, 24576);
    k_pack16<<<16, 256, 0, stream>>>(dec_w1, d1f, 4, 4, 64, 4096);

    k_encoder<<<dim3(X_ / 64, B_), 256, 0, stream>>>(xin, enc_w, enc_b, psiA);

    const _Float16* cur = psiA;
    _Float16* nxt = psiB;
    for (int t = 0; t < TOUT; ++t) {
        for (int i = 0; i < DEPTH; ++i) {
            float* yout = (i == DEPTH - 1) ? out : nullptr;
            k_layer<<<dim3(X_ / TILE, B_), 256, 0, stream>>>(
                cur, nxt,
                cwf + i * 20480, conv_b + i * H_,
                w1f + i * 8192,  mlp_b1 + i * F_,
                w2f + i * 8192,  mlp_b2 + i * H_,
                ln_g + i * H_, ln_b + i * H_,
                d1f, dec_b1, dec_w2, dec_b2, yout, t);
            _Float16* tmp = (_Float16*)cur; cur = nxt; nxt = tmp;
        }
    }
}

// Round 22
// 4175.311 us; speedup vs baseline: 1.0270x; 1.0270x over previous
//
#include <hip/hip_runtime.h>
#include <hip/hip_bf16.h>
#include <hip/hip_fp16.h>

#define B_   32
#define TIN  16
#define X_   8192
#define H_   64
#define F_   128
#define K_   5
#define DEPTH 3
#define TOUT 32
#define TILE 256          // 4 waves x 64 x-columns (4 col-groups each)
#define PROW (X_ + 4)     // padded rows per batch: 2 zero | X | 2 zero

typedef __attribute__((ext_vector_type(8))) _Float16 h16x8;
typedef __attribute__((ext_vector_type(4))) _Float16 h16x4;
typedef __attribute__((ext_vector_type(2))) _Float16 h16x2;
typedef __attribute__((ext_vector_type(2))) __fp16 fp16x2;
typedef __attribute__((ext_vector_type(4))) float f32x4;

// GELU via A&S 7.1.25 3-term erf (fp32, used in decoder head only)
__device__ __forceinline__ float gelu_fast(float z) {
    float t = fminf(fabsf(z) * 0.70710678118654752f, 3.9192f);
    float w = __builtin_amdgcn_rcpf(__builtin_fmaf(0.47047f, t, 1.0f));
    float p = w * __builtin_fmaf(w, __builtin_fmaf(w, 0.7478556f, -0.0958798f), 0.3480242f);
    float e = __expf(-t * t);
    float erf_abs = __builtin_fmaf(-p, e, 1.0f);
    return 0.5f * z * (1.0f + copysignf(erf_abs, z));
}

// packed-fp16 GELU: f32x4 -> h16x4 via cvt_pkrtz + __half2 A&S 7.1.25
// (regular ops packed 2-wide; exp/rcp stay per-element trans ops)
__device__ __forceinline__ h16x4 gelu4(f32x4 v) {
    union HU { __half2 h; h16x2 v; fp16x2 f; unsigned u; };
    const __half2 k1  = __float2half2_rn(1.0f);
    const __half2 kP  = __float2half2_rn(0.47047f);
    const __half2 kA1 = __float2half2_rn(0.3480242f);
    const __half2 kA2 = __float2half2_rn(-0.0958798f);
    const __half2 kA3 = __float2half2_rn(0.7478556f);
    const __half2 kH  = __float2half2_rn(0.5f);
    const __half2 kC  = __float2half2_rn(0.70710678f);
    h16x4 out;
    #pragma unroll
    for (int p2 = 0; p2 < 2; ++p2) {
        HU z; z.f = __builtin_amdgcn_cvt_pkrtz(v[p2 * 2], v[p2 * 2 + 1]);
        HU az; az.u = z.u & 0x7FFF7FFFu;                      // |z|
        __half2 t = __hmul2(az.h, kC);
        __half2 w = h2rcp(__hfma2(kP, t, k1));
        __half2 p = __hmul2(w, __hfma2(w, __hfma2(w, kA3, kA2), kA1));
        __half2 e = h2exp(__hneg2(__hmul2(t, t)));
        HU erf; erf.h = __hfma2(__hneg2(p), e, k1);           // 1 - p*e  (>= 0)
        HU erfs; erfs.u = erf.u | (z.u & 0x80008000u);        // copysign(erf, z)
        __half2 g = __hmul2(z.h, __hfma2(kH, erfs.h, kH));    // z*(0.5+0.5*erf)
        HU go; go.h = g;
        out[p2 * 2]     = go.v[0];
        out[p2 * 2 + 1] = go.v[1];
    }
    return out;
}

// swizzled LDS address: row stride rb bytes, XOR (row&7)<<4 spreads banks
__device__ __forceinline__ char* lp(void* base, int row, int cb, int rb) {
    return (char*)base + row * rb + (cb ^ ((row & 7) << 4));
}
// 16x32 activation fragment from swizzled LDS (B role): lane -> (x=row, d=kt*32+l4*8+e)
__device__ __forceinline__ h16x8 lda(const void* base, int row, int kt, int rb, int lane) {
    return *(const h16x8*)((const char*)base + row * rb +
                           ((kt * 64 + ((lane >> 4) << 4)) ^ ((row & 7) << 4)));
}
// packed weight fragments: contiguous per fragment, fully coalesced wave reads
__device__ __forceinline__ h16x4 ldp16(const _Float16* w, int frag, int lane) {
    return *(const h16x4*)&w[(frag << 8) + (lane << 2)];
}
__device__ __forceinline__ h16x8 ldp32(const _Float16* w, int frag, int lane) {
    return *(const h16x8*)&w[(frag << 9) + (lane << 3)];
}

__device__ __forceinline__ f32x4 mfma32(h16x8 a, h16x8 b, f32x4 c) {
    return __builtin_amdgcn_mfma_f32_16x16x32_f16(a, b, c, 0, 0, 0);
}
__device__ __forceinline__ f32x4 mfma16(h16x4 a, h16x4 b, f32x4 c) {
    return __builtin_amdgcn_mfma_f32_16x16x16f16(a, b, c, 0, 0, 0);
}

// ---------------- weight prep: fp32 -> packed fp16 fragments ----------------
__global__ __launch_bounds__(256) void k_prep_conv(const float* __restrict__ s,
                                                   _Float16* __restrict__ w) {
    int t = blockIdx.x * 256 + threadIdx.x;
    if (t >= DEPTH * 20480) return;
    int i = t / 20480, r = t % 20480;
    int frag = r >> 9, lane = (r >> 3) & 63, e = r & 7;
    int k = frag >> 3, kt = (frag >> 2) & 1, nt = frag & 3;
    int o = nt * 16 + (lane & 15);
    int d = kt * 32 + ((lane >> 4) << 3) + e;
    w[t] = (_Float16)s[((i * 64 + o) * 64 + d) * 5 + k];
}
__global__ __launch_bounds__(256) void k_pack16(const float* __restrict__ s,
                                                _Float16* __restrict__ w,
                                                int NT, int KT, int K, int total) {
    int t = blockIdx.x * 256 + threadIdx.x;
    if (t >= total) return;
    int per = NT * KT * 256;
    int li = t / per, r = t % per;
    int frag = r >> 8, lane = (r >> 2) & 63, e = r & 3;
    int kt = frag / NT, nt = frag % NT;
    int n = nt * 16 + (lane & 15);
    int kk = kt * 16 + ((lane >> 4) << 2) + e;
    w[t] = (_Float16)s[li * (NT * 16 * K) + n * K + kk];
}

// zero the halo pad rows of both psi buffers (rows 0,1 and X+2,X+3 per batch)
__global__ __launch_bounds__(256) void k_zero_pads(_Float16* __restrict__ pA,
                                                   _Float16* __restrict__ pB) {
    int i = blockIdx.x * 256 + threadIdx.x;      // over B*4*64
    if (i >= B_ * 4 * 64) return;
    int b = i >> 8, r = (i >> 6) & 3, h = i & 63;
    int row = (r < 2) ? r : (X_ + r);            // 0,1,X+2,X+3
    size_t off = ((size_t)b * PROW + row) * H_ + h;
    pA[off] = (_Float16)0.f;
    pB[off] = (_Float16)0.f;
}

// ---------------- encoder (runs once; fp32 VALU, writes fp16 padded psi) ----------------
__global__ __launch_bounds__(256) void k_encoder(const float* __restrict__ xin,
                                                 const float* __restrict__ enc_w,
                                                 const float* __restrict__ enc_b,
                                                 _Float16* __restrict__ psi) {
    const int b  = blockIdx.y;
    const int x0 = blockIdx.x * 64;
    __shared__ float s_x[TIN][64];
    __shared__ float s_w[TIN][H_];
    __shared__ float s_p[64][H_];
    const int tid = threadIdx.x;

    for (int idx = tid; idx < TIN * 64; idx += 256) {
        int t = idx >> 6, xl = idx & 63;
        s_x[t][xl] = xin[((size_t)b * TIN + t) * X_ + x0 + xl];
    }
    for (int idx = tid; idx < TIN * H_; idx += 256) {
        int t = idx >> 6, h = idx & 63;
        s_w[t][h] = enc_w[h * TIN + t];
    }
    __syncthreads();
    {
        int h = tid & 63, grp = tid >> 6;
        float bias = enc_b[h];
        for (int r = 0; r < 16; ++r) {
            int xl = grp * 16 + r;
            float acc = bias;
            #pragma unroll
            for (int t = 0; t < TIN; ++t) acc += s_x[t][xl] * s_w[t][h];
            s_p[xl][h] = acc;
        }
    }
    __syncthreads();
    {
        int lane = tid & 63, wv = tid >> 6;
        for (int r = 0; r < 16; ++r) {
            int xl = wv * 16 + r;
            float v = s_p[xl][lane];
            float s = v;
            #pragma unroll
            for (int off = 32; off; off >>= 1) s += __shfl_xor(s, off);
            float mu = s * (1.0f / 64.0f);
            float dv = v - mu;
            float q = dv * dv;
            #pragma unroll
            for (int off = 32; off; off >>= 1) q += __shfl_xor(q, off);
            float sd = sqrtf(q * (1.0f / 63.0f)) + 1e-6f;
            psi[((size_t)b * PROW + 2 + x0 + xl) * H_ + lane] = (_Float16)(dv / sd);
        }
    }
}

// ---------------- fused layer: M=64/wave, register chain, FULL-LINE output stores ----------------
// psi fp16 padded [b][2|X|2][64]. TILE=256, 4 waves x 64 cols (4 cgs).
// Residual read from sA. After mlp2: barrier, LN writes into dead sA, each
// wave copies its 64 rows out as full 128B lines. launch_bounds (256,2):
// <=2 blocks/CU so streaming footprint stays <= ~128 KB/CU L2 share.
// mlp1 gelu computed in packed fp16 (cvt_pkrtz + v_pk ops).
__global__ __launch_bounds__(256, 2) void k_layer(const _Float16* __restrict__ pin,
                                                  _Float16* __restrict__ pout,
                                                  const _Float16* __restrict__ cw,
                                                  const float* __restrict__ cb,
                                                  const _Float16* __restrict__ w1,
                                                  const float* __restrict__ b1,
                                                  const _Float16* __restrict__ w2,
                                                  const float* __restrict__ b2,
                                                  const float* __restrict__ g,
                                                  const float* __restrict__ bt,
                                                  const _Float16* __restrict__ d1,
                                                  const float* __restrict__ b1d,
                                                  const float* __restrict__ w2d,
                                                  const float* __restrict__ b2d,
                                                  float* __restrict__ yout, int step) {
    __shared__ __align__(16) _Float16 sA[(TILE + 4) * 64];   // 260 rows x 128B = 33.3 KB

    const int tid  = threadIdx.x;
    const int b    = blockIdx.y;
    const int x0   = blockIdx.x * TILE;
    const int lane = tid & 63, wv = tid >> 6;
    const int l15  = lane & 15, l4 = lane >> 4;
    const int XW   = wv * 64;                 // wave owns 64 x-columns
    const int xg0  = x0 + XW + l15;

    // ---- stage psi rows: padded rows [x0, x0+260) = global x [x0-2, x0+258)
    {
        const _Float16* src = pin + ((size_t)b * PROW + x0) * H_;
        for (int idx = tid; idx < (TILE + 4) * 8; idx += 256) {
            int r = idx >> 3, c8 = idx & 7;
            h16x8 v = *(const h16x8*)(src + r * H_ + c8 * 8);
            *(h16x8*)lp(sA, r, c8 * 16, 128) = v;
        }
    }
    __syncthreads();   // barrier 1: sA staged

    // ---- conv (K=32, swapped): acc[cg][nt]; each weight frag feeds 4 cgs
    f32x4 acc[4][4];
    #pragma unroll
    for (int nt = 0; nt < 4; ++nt) {
        f32x4 bb = *(const f32x4*)&cb[nt * 16 + (l4 << 2)];
        #pragma unroll
        for (int cg = 0; cg < 4; ++cg) acc[cg][nt] = bb;
    }
    #pragma unroll
    for (int k = 0; k < K_; ++k) {
        h16x8 bfrag[4][2];
        #pragma unroll
        for (int cg = 0; cg < 4; ++cg) {
            bfrag[cg][0] = lda(sA, XW + cg * 16 + l15 + k, 0, 128, lane);
            bfrag[cg][1] = lda(sA, XW + cg * 16 + l15 + k, 1, 128, lane);
        }
        #pragma unroll
        for (int nt = 0; nt < 4; ++nt) {
            h16x8 a0 = ldp32(cw, (k * 2 + 0) * 4 + nt, lane);
            h16x8 a1 = ldp32(cw, (k * 2 + 1) * 4 + nt, lane);
            #pragma unroll
            for (int cg = 0; cg < 4; ++cg) {
                acc[cg][nt] = mfma32(a0, bfrag[cg][0], acc[cg][nt]);
                acc[cg][nt] = mfma32(a1, bfrag[cg][1], acc[cg][nt]);
            }
        }
    }
    h16x4 hb[4][4];
    #pragma unroll
    for (int cg = 0; cg < 4; ++cg)
        #pragma unroll
        for (int nt = 0; nt < 4; ++nt) {
            #pragma unroll
            for (int j = 0; j < 4; ++j) hb[cg][nt][j] = (_Float16)acc[cg][nt][j];
        }

    // ---- mlp1 (K=16, swapped): m[f][x] = W1 . h ; each frag feeds 4 cgs
    f32x4 m[4][8];
    #pragma unroll
    for (int ft = 0; ft < 8; ++ft) {
        f32x4 bb = *(const f32x4*)&b1[ft * 16 + (l4 << 2)];
        #pragma unroll
        for (int cg = 0; cg < 4; ++cg) m[cg][ft] = bb;
    }
    #pragma unroll
    for (int kt = 0; kt < 4; ++kt) {
        #pragma unroll
        for (int ft = 0; ft < 8; ++ft) {
            h16x4 aw = ldp16(w1, kt * 8 + ft, lane);
            #pragma unroll
            for (int cg = 0; cg < 4; ++cg) m[cg][ft] = mfma16(aw, hb[cg][kt], m[cg][ft]);
        }
    }

    // ---- gelu in packed fp16 (long VALU phase); m dies here
    h16x4 mb[4][8];
    #pragma unroll
    for (int cg = 0; cg < 4; ++cg)
        #pragma unroll
        for (int ft = 0; ft < 8; ++ft) mb[cg][ft] = gelu4(m[cg][ft]);

    // ---- residual from sA (same fp16 values; saves global loads)
    h16x4 res[4][4];
    #pragma unroll
    for (int cg = 0; cg < 4; ++cg) {
        int ri = 2 + XW + cg * 16 + l15;
        #pragma unroll
        for (int nt = 0; nt < 4; ++nt)
            res[cg][nt] = *(const h16x4*)lp(sA, ri, nt * 32 + (l4 << 3), 128);
    }

    // ---- mlp2 (K=16, swapped): o[d][x] = W2 . m ; each frag feeds 4 cgs
    f32x4 o[4][4];
    #pragma unroll
    for (int nt = 0; nt < 4; ++nt) {
        f32x4 bb = *(const f32x4*)&b2[nt * 16 + (l4 << 2)];
        #pragma unroll
        for (int cg = 0; cg < 4; ++cg) o[cg][nt] = bb;
    }
    #pragma unroll
    for (int kt = 0; kt < 8; ++kt) {
        #pragma unroll
        for (int nt = 0; nt < 4; ++nt) {
            h16x4 aw = ldp16(w2, kt * 4 + nt, lane);
            #pragma unroll
            for (int cg = 0; cg < 4; ++cg) o[cg][nt] = mfma16(aw, mb[cg][kt], o[cg][nt]);
        }
    }

    __syncthreads();   // barrier 2: all waves' sA reads (conv halo + residual) done

    // ---- residual + LN + clip -> ps regs + write into dead sA (wave-private rows)
    h16x4 ps[4][4];
    #pragma unroll
    for (int cg = 0; cg < 4; ++cg) {
        float v[4][4];
        float s = 0.f;
        #pragma unroll
        for (int nt = 0; nt < 4; ++nt) {
            #pragma unroll
            for (int j = 0; j < 4; ++j) {
                v[nt][j] = o[cg][nt][j] + (float)res[cg][nt][j];
                s += v[nt][j];
            }
        }
        s += __shfl_xor(s, 16); s += __shfl_xor(s, 32);
        float mu = s * (1.0f / 64.0f);
        float q = 0.f;
        #pragma unroll
        for (int nt = 0; nt < 4; ++nt) {
            #pragma unroll
            for (int j = 0; j < 4; ++j) { v[nt][j] -= mu; q += v[nt][j] * v[nt][j]; }
        }
        q += __shfl_xor(q, 16); q += __shfl_xor(q, 32);
        float rs = rsqrtf(q * (1.0f / 64.0f) + 1e-5f);
        int ri = 2 + XW + cg * 16 + l15;
        #pragma unroll
        for (int nt = 0; nt < 4; ++nt) {
            f32x4 gg = *(const f32x4*)&g[nt * 16 + (l4 << 2)];
            f32x4 bb = *(const f32x4*)&bt[nt * 16 + (l4 << 2)];
            #pragma unroll
            for (int j = 0; j < 4; ++j) {
                float ov = v[nt][j] * rs * gg[j] + bb[j];
                ov = fminf(10.0f, fmaxf(-10.0f, ov));
                ps[cg][nt][j] = (_Float16)ov;
            }
            *(h16x4*)lp(sA, ri, nt * 32 + (l4 << 3), 128) = ps[cg][nt];
        }
    }

    // ---- copy-out: full 128B lines, wave-private rows [XW, XW+64)
    {
        _Float16* dst = pout + ((size_t)b * PROW + 2 + x0 + XW) * H_;
        int lr = lane >> 3, c8 = lane & 7;        // 8 rows x 8 chunks per iter
        #pragma unroll
        for (int it = 0; it < 8; ++it) {
            int r = it * 8 + lr;                  // row within wave slab [0,64)
            h16x8 v = *(const h16x8*)lp(sA, 2 + XW + r, c8 * 16, 128);
            *(h16x8*)(dst + r * H_ + c8 * 8) = v;
        }
    }

    // ---- fused decoder head (depth 2 only; fp32 gelu — feeds y directly)
    if (yout) {
        f32x4 dacc[4][4];
        #pragma unroll
        for (int ht = 0; ht < 4; ++ht) {
            f32x4 bb = *(const f32x4*)&b1d[ht * 16 + (l4 << 2)];
            #pragma unroll
            for (int cg = 0; cg < 4; ++cg) dacc[cg][ht] = bb;
        }
        #pragma unroll
        for (int kt = 0; kt < 4; ++kt) {
            #pragma unroll
            for (int ht = 0; ht < 4; ++ht) {
                h16x4 aw = ldp16(d1, kt * 4 + ht, lane);
                #pragma unroll
                for (int cg = 0; cg < 4; ++cg) dacc[cg][ht] = mfma16(aw, ps[cg][kt], dacc[cg][ht]);
            }
        }
        float y[4] = {0.f, 0.f, 0.f, 0.f};
        #pragma unroll
        for (int ht = 0; ht < 4; ++ht) {
            f32x4 wq = *(const f32x4*)&w2d[ht * 16 + (l4 << 2)];
            #pragma unroll
            for (int cg = 0; cg < 4; ++cg) {
                #pragma unroll
                for (int j = 0; j < 4; ++j) y[cg] += gelu_fast(dacc[cg][ht][j]) * wq[j];
            }
        }
        #pragma unroll
        for (int cg = 0; cg < 4; ++cg) {
            y[cg] += __shfl_xor(y[cg], 16);
            y[cg] += __shfl_xor(y[cg], 32);
        }
        if (l4 == 0) {
            size_t ybase = ((size_t)b * TOUT + step) * X_;
            #pragma unroll
            for (int cg = 0; cg < 4; ++cg)
                yout[ybase + xg0 + cg * 16] = y[cg] + b2d[0];
        }
    }
}

extern "C" void kernel_launch(void* const* d_in, const int* in_sizes, int n_in,
                              void* d_out, int out_size, void* d_ws, size_t ws_size,
                              hipStream_t stream) {
    const float* xin    = (const float*)d_in[0];
    const float* enc_w  = (const float*)d_in[1];
    const float* enc_b  = (const float*)d_in[2];
    const float* conv_w = (const float*)d_in[3];
    const float* conv_b = (const float*)d_in[4];
    const float* mlp_w1 = (const float*)d_in[5];
    const float* mlp_b1 = (const float*)d_in[6];
    const float* mlp_w2 = (const float*)d_in[7];
    const float* mlp_b2 = (const float*)d_in[8];
    const float* ln_g   = (const float*)d_in[9];
    const float* ln_b   = (const float*)d_in[10];
    const float* dec_w1 = (const float*)d_in[11];
    const float* dec_b1 = (const float*)d_in[12];
    const float* dec_w2 = (const float*)d_in[13];
    const float* dec_b2 = (const float*)d_in[14];
    float* out = (float*)d_out;

    const size_t PSI = (size_t)B_ * PROW * H_;       // fp16 elements
    _Float16* psiA = (_Float16*)d_ws;
    _Float16* psiB = psiA + PSI;
    _Float16* cwf = psiB + PSI;               // [3][40 frags][512]
    _Float16* w1f = cwf + 61440;              // [3][32 frags][256]
    _Float16* w2f = w1f + 24576;              // [3][32 frags][256]
    _Float16* d1f = w2f + 24576;              // [16 frags][256]
    (void)ws_size; (void)n_in; (void)in_sizes; (void)out_size;

    k_zero_pads<<<32, 256, 0, stream>>>(psiA, psiB);
    k_prep_conv<<<240, 256, 0, stream>>>(conv_w, cwf);
    k_pack16<<<96, 256, 0, stream>>>(mlp_w1, w1f, 8, 4, 64, 24576);
    k_pack16<<<96, 256, 0, stream>>>(mlp_w2, w2f, 4, 8, 128, 24576);
    k_pack16<<<16, 256, 0, stream>>>(dec_w1, d1f, 4, 4, 64, 4096);

    k_encoder<<<dim3(X_ / 64, B_), 256, 0, stream>>>(xin, enc_w, enc_b, psiA);

    const _Float16* cur = psiA;
    _Float16* nxt = psiB;
    for (int t = 0; t < TOUT; ++t) {
        for (int i = 0; i < DEPTH; ++i) {
            float* yout = (i == DEPTH - 1) ? out : nullptr;
            k_layer<<<dim3(X_ / TILE, B_), 256, 0, stream>>>(
                cur, nxt,
                cwf + i * 20480, conv_b + i * H_,
                w1f + i * 8192,  mlp_b1 + i * F_,
                w2f + i * 8192,  mlp_b2 + i * H_,
                ln_g + i * H_, ln_b + i * H_,
                d1f, dec_b1, dec_w2, dec_b2, yout, t);
            _Float16* tmp = (_Float16*)cur; cur = nxt; nxt = tmp;
        }
    }
}

// Round 23
// 4096.717 us; speedup vs baseline: 1.0467x; 1.0192x over previous
//
#include <hip/hip_runtime.h>
#include <hip/hip_bf16.h>
#include <hip/hip_fp16.h>

#define B_   32
#define TIN  16
#define X_   8192
#define H_   64
#define F_   128
#define K_   5
#define DEPTH 3
#define TOUT 32
#define TILE 256          // 4 waves x 64 x-columns (4 col-groups each)
#define PROW (X_ + 4)     // padded rows per batch: 2 zero | X | 2 zero

typedef __attribute__((ext_vector_type(8))) _Float16 h16x8;
typedef __attribute__((ext_vector_type(4))) _Float16 h16x4;
typedef __attribute__((ext_vector_type(2))) _Float16 h16x2;
typedef __attribute__((ext_vector_type(2))) __fp16 fp16x2;
typedef __attribute__((ext_vector_type(4))) float f32x4;

// GELU via A&S 7.1.25 3-term erf (fp32, used in decoder head only)
__device__ __forceinline__ float gelu_fast(float z) {
    float t = fminf(fabsf(z) * 0.70710678118654752f, 3.9192f);
    float w = __builtin_amdgcn_rcpf(__builtin_fmaf(0.47047f, t, 1.0f));
    float p = w * __builtin_fmaf(w, __builtin_fmaf(w, 0.7478556f, -0.0958798f), 0.3480242f);
    float e = __expf(-t * t);
    float erf_abs = __builtin_fmaf(-p, e, 1.0f);
    return 0.5f * z * (1.0f + copysignf(erf_abs, z));
}

// packed-fp16 GELU: f32x4 -> h16x4 via cvt_pkrtz + __half2 A&S 7.1.25
__device__ __forceinline__ h16x4 gelu4(f32x4 v) {
    union HU { __half2 h; h16x2 v; fp16x2 f; unsigned u; };
    const __half2 k1  = __float2half2_rn(1.0f);
    const __half2 kP  = __float2half2_rn(0.47047f);
    const __half2 kA1 = __float2half2_rn(0.3480242f);
    const __half2 kA2 = __float2half2_rn(-0.0958798f);
    const __half2 kA3 = __float2half2_rn(0.7478556f);
    const __half2 kH  = __float2half2_rn(0.5f);
    const __half2 kC  = __float2half2_rn(0.70710678f);
    h16x4 out;
    #pragma unroll
    for (int p2 = 0; p2 < 2; ++p2) {
        HU z; z.f = __builtin_amdgcn_cvt_pkrtz(v[p2 * 2], v[p2 * 2 + 1]);
        HU az; az.u = z.u & 0x7FFF7FFFu;                      // |z|
        __half2 t = __hmul2(az.h, kC);
        __half2 w = h2rcp(__hfma2(kP, t, k1));
        __half2 p = __hmul2(w, __hfma2(w, __hfma2(w, kA3, kA2), kA1));
        __half2 e = h2exp(__hneg2(__hmul2(t, t)));
        HU erf; erf.h = __hfma2(__hneg2(p), e, k1);           // 1 - p*e  (>= 0)
        HU erfs; erfs.u = erf.u | (z.u & 0x80008000u);        // copysign(erf, z)
        __half2 g = __hmul2(z.h, __hfma2(kH, erfs.h, kH));    // z*(0.5+0.5*erf)
        HU go; go.h = g;
        out[p2 * 2]     = go.v[0];
        out[p2 * 2 + 1] = go.v[1];
    }
    return out;
}

// swizzled LDS address: row stride rb bytes, XOR (row&7)<<4 spreads banks
__device__ __forceinline__ char* lp(void* base, int row, int cb, int rb) {
    return (char*)base + row * rb + (cb ^ ((row & 7) << 4));
}
// 16x32 activation fragment from swizzled LDS (B role): lane -> (x=row, d=kt*32+l4*8+e)
__device__ __forceinline__ h16x8 lda(const void* base, int row, int kt, int rb, int lane) {
    return *(const h16x8*)((const char*)base + row * rb +
                           ((kt * 64 + ((lane >> 4) << 4)) ^ ((row & 7) << 4)));
}
// packed weight fragments: contiguous per fragment, fully coalesced wave reads
__device__ __forceinline__ h16x4 ldp16(const _Float16* w, int frag, int lane) {
    return *(const h16x4*)&w[(frag << 8) + (lane << 2)];
}
__device__ __forceinline__ h16x8 ldp32(const _Float16* w, int frag, int lane) {
    return *(const h16x8*)&w[(frag << 9) + (lane << 3)];
}

__device__ __forceinline__ f32x4 mfma32(h16x8 a, h16x8 b, f32x4 c) {
    return __builtin_amdgcn_mfma_f32_16x16x32_f16(a, b, c, 0, 0, 0);
}
__device__ __forceinline__ f32x4 mfma16(h16x4 a, h16x4 b, f32x4 c) {
    return __builtin_amdgcn_mfma_f32_16x16x16f16(a, b, c, 0, 0, 0);
}

// ---------------- weight prep: fp32 -> packed fp16 fragments ----------------
__global__ __launch_bounds__(256) void k_prep_conv(const float* __restrict__ s,
                                                   _Float16* __restrict__ w) {
    int t = blockIdx.x * 256 + threadIdx.x;
    if (t >= DEPTH * 20480) return;
    int i = t / 20480, r = t % 20480;
    int frag = r >> 9, lane = (r >> 3) & 63, e = r & 7;
    int k = frag >> 3, kt = (frag >> 2) & 1, nt = frag & 3;
    int o = nt * 16 + (lane & 15);
    int d = kt * 32 + ((lane >> 4) << 3) + e;
    w[t] = (_Float16)s[((i * 64 + o) * 64 + d) * 5 + k];
}
__global__ __launch_bounds__(256) void k_pack16(const float* __restrict__ s,
                                                _Float16* __restrict__ w,
                                                int NT, int KT, int K, int total) {
    int t = blockIdx.x * 256 + threadIdx.x;
    if (t >= total) return;
    int per = NT * KT * 256;
    int li = t / per, r = t % per;
    int frag = r >> 8, lane = (r >> 2) & 63, e = r & 3;
    int kt = frag / NT, nt = frag % NT;
    int n = nt * 16 + (lane & 15);
    int kk = kt * 16 + ((lane >> 4) << 2) + e;
    w[t] = (_Float16)s[li * (NT * 16 * K) + n * K + kk];
}

// zero the halo pad rows of both psi buffers (rows 0,1 and X+2,X+3 per batch)
__global__ __launch_bounds__(256) void k_zero_pads(_Float16* __restrict__ pA,
                                                   _Float16* __restrict__ pB) {
    int i = blockIdx.x * 256 + threadIdx.x;      // over B*4*64
    if (i >= B_ * 4 * 64) return;
    int b = i >> 8, r = (i >> 6) & 3, h = i & 63;
    int row = (r < 2) ? r : (X_ + r);            // 0,1,X+2,X+3
    size_t off = ((size_t)b * PROW + row) * H_ + h;
    pA[off] = (_Float16)0.f;
    pB[off] = (_Float16)0.f;
}

// ---------------- encoder (runs once; fp32 VALU, writes fp16 padded psi) ----------------
__global__ __launch_bounds__(256) void k_encoder(const float* __restrict__ xin,
                                                 const float* __restrict__ enc_w,
                                                 const float* __restrict__ enc_b,
                                                 _Float16* __restrict__ psi) {
    const int b  = blockIdx.y;
    const int x0 = blockIdx.x * 64;
    __shared__ float s_x[TIN][64];
    __shared__ float s_w[TIN][H_];
    __shared__ float s_p[64][H_];
    const int tid = threadIdx.x;

    for (int idx = tid; idx < TIN * 64; idx += 256) {
        int t = idx >> 6, xl = idx & 63;
        s_x[t][xl] = xin[((size_t)b * TIN + t) * X_ + x0 + xl];
    }
    for (int idx = tid; idx < TIN * H_; idx += 256) {
        int t = idx >> 6, h = idx & 63;
        s_w[t][h] = enc_w[h * TIN + t];
    }
    __syncthreads();
    {
        int h = tid & 63, grp = tid >> 6;
        float bias = enc_b[h];
        for (int r = 0; r < 16; ++r) {
            int xl = grp * 16 + r;
            float acc = bias;
            #pragma unroll
            for (int t = 0; t < TIN; ++t) acc += s_x[t][xl] * s_w[t][h];
            s_p[xl][h] = acc;
        }
    }
    __syncthreads();
    {
        int lane = tid & 63, wv = tid >> 6;
        for (int r = 0; r < 16; ++r) {
            int xl = wv * 16 + r;
            float v = s_p[xl][lane];
            float s = v;
            #pragma unroll
            for (int off = 32; off; off >>= 1) s += __shfl_xor(s, off);
            float mu = s * (1.0f / 64.0f);
            float dv = v - mu;
            float q = dv * dv;
            #pragma unroll
            for (int off = 32; off; off >>= 1) q += __shfl_xor(q, off);
            float sd = sqrtf(q * (1.0f / 63.0f)) + 1e-6f;
            psi[((size_t)b * PROW + 2 + x0 + xl) * H_ + lane] = (_Float16)(dv / sd);
        }
    }
}

// ---------------- fused layer: M=64/wave, register chain, FULL-LINE output stores ----------------
// psi fp16 padded [b][2|X|2][64]. TILE=256, 4 waves x 64 cols (4 cgs).
// Staging via global_load_lds (direct HBM/L2 -> LDS, no VGPR round-trip):
// LDS dest is linear (wave base + lane*16); the XOR bank-swizzle (involution
// in 16B units: c8 ^= row&7) is pre-applied to the per-lane GLOBAL source, so
// LDS bytes land exactly where the swizzled readers (lda/lp) expect them.
__global__ __launch_bounds__(256, 2) void k_layer(const _Float16* __restrict__ pin,
                                                  _Float16* __restrict__ pout,
                                                  const _Float16* __restrict__ cw,
                                                  const float* __restrict__ cb,
                                                  const _Float16* __restrict__ w1,
                                                  const float* __restrict__ b1,
                                                  const _Float16* __restrict__ w2,
                                                  const float* __restrict__ b2,
                                                  const float* __restrict__ g,
                                                  const float* __restrict__ bt,
                                                  const _Float16* __restrict__ d1,
                                                  const float* __restrict__ b1d,
                                                  const float* __restrict__ w2d,
                                                  const float* __restrict__ b2d,
                                                  float* __restrict__ yout, int step) {
    __shared__ __align__(16) _Float16 sA[(TILE + 4) * 64];   // 260 rows x 128B = 33.3 KB

    const int tid  = threadIdx.x;
    const int b    = blockIdx.y;
    const int x0   = blockIdx.x * TILE;
    const int lane = tid & 63, wv = tid >> 6;
    const int l15  = lane & 15, l4 = lane >> 4;
    const int XW   = wv * 64;                 // wave owns 64 x-columns
    const int xg0  = x0 + XW + l15;

    // ---- stage psi rows [x0, x0+260): 2080 16B slots, slot s -> row r=s>>3, swz-col c8=s&7
#if defined(__has_builtin) && __has_builtin(__builtin_amdgcn_global_load_lds)
    {
        const _Float16* src = pin + ((size_t)b * PROW + x0) * H_;
        #pragma unroll
        for (int i = 0; i < 9; ++i) {
            int s = i * 256 + tid;
            bool act = (i < 8) || (s < (TILE + 4) * 8);
            if (act) {
                int r = s >> 3, c8 = s & 7;
                int c8u = c8 ^ (r & 7);                       // inverse of the read swizzle
                const _Float16* gp = src + r * H_ + c8u * 8;
                // wave-uniform LDS base: slot (i*256 + wv*64), lane offset auto (+lane*16)
                _Float16* lbase = sA + (size_t)(i * 256 + wv * 64) * 8;
                __builtin_amdgcn_global_load_lds(
                    (const __attribute__((address_space(1))) unsigned int*)gp,
                    (__attribute__((address_space(3))) unsigned int*)lbase,
                    16, 0, 0);
            }
        }
    }
#else
    {
        const _Float16* src = pin + ((size_t)b * PROW + x0) * H_;
        for (int idx = tid; idx < (TILE + 4) * 8; idx += 256) {
            int r = idx >> 3, c8 = idx & 7;
            h16x8 v = *(const h16x8*)(src + r * H_ + c8 * 8);
            *(h16x8*)lp(sA, r, c8 * 16, 128) = v;
        }
    }
#endif
    __syncthreads();   // barrier 1: sA staged (vmcnt(0) drains global_load_lds)

    // ---- conv (K=32, swapped): acc[cg][nt]; each weight frag feeds 4 cgs
    f32x4 acc[4][4];
    #pragma unroll
    for (int nt = 0; nt < 4; ++nt) {
        f32x4 bb = *(const f32x4*)&cb[nt * 16 + (l4 << 2)];
        #pragma unroll
        for (int cg = 0; cg < 4; ++cg) acc[cg][nt] = bb;
    }
    #pragma unroll
    for (int k = 0; k < K_; ++k) {
        h16x8 bfrag[4][2];
        #pragma unroll
        for (int cg = 0; cg < 4; ++cg) {
            bfrag[cg][0] = lda(sA, XW + cg * 16 + l15 + k, 0, 128, lane);
            bfrag[cg][1] = lda(sA, XW + cg * 16 + l15 + k, 1, 128, lane);
        }
        #pragma unroll
        for (int nt = 0; nt < 4; ++nt) {
            h16x8 a0 = ldp32(cw, (k * 2 + 0) * 4 + nt, lane);
            h16x8 a1 = ldp32(cw, (k * 2 + 1) * 4 + nt, lane);
            #pragma unroll
            for (int cg = 0; cg < 4; ++cg) {
                acc[cg][nt] = mfma32(a0, bfrag[cg][0], acc[cg][nt]);
                acc[cg][nt] = mfma32(a1, bfrag[cg][1], acc[cg][nt]);
            }
        }
    }
    h16x4 hb[4][4];
    #pragma unroll
    for (int cg = 0; cg < 4; ++cg)
        #pragma unroll
        for (int nt = 0; nt < 4; ++nt) {
            #pragma unroll
            for (int j = 0; j < 4; ++j) hb[cg][nt][j] = (_Float16)acc[cg][nt][j];
        }

    // ---- mlp1 (K=16, swapped): m[f][x] = W1 . h ; each frag feeds 4 cgs
    f32x4 m[4][8];
    #pragma unroll
    for (int ft = 0; ft < 8; ++ft) {
        f32x4 bb = *(const f32x4*)&b1[ft * 16 + (l4 << 2)];
        #pragma unroll
        for (int cg = 0; cg < 4; ++cg) m[cg][ft] = bb;
    }
    #pragma unroll
    for (int kt = 0; kt < 4; ++kt) {
        #pragma unroll
        for (int ft = 0; ft < 8; ++ft) {
            h16x4 aw = ldp16(w1, kt * 8 + ft, lane);
            #pragma unroll
            for (int cg = 0; cg < 4; ++cg) m[cg][ft] = mfma16(aw, hb[cg][kt], m[cg][ft]);
        }
    }

    // ---- gelu in packed fp16 (long VALU phase); m dies here
    h16x4 mb[4][8];
    #pragma unroll
    for (int cg = 0; cg < 4; ++cg)
        #pragma unroll
        for (int ft = 0; ft < 8; ++ft) mb[cg][ft] = gelu4(m[cg][ft]);

    // ---- residual from sA (same fp16 values; saves global loads)
    h16x4 res[4][4];
    #pragma unroll
    for (int cg = 0; cg < 4; ++cg) {
        int ri = 2 + XW + cg * 16 + l15;
        #pragma unroll
        for (int nt = 0; nt < 4; ++nt)
            res[cg][nt] = *(const h16x4*)lp(sA, ri, nt * 32 + (l4 << 3), 128);
    }

    // ---- mlp2 (K=16, swapped): o[d][x] = W2 . m ; each frag feeds 4 cgs
    f32x4 o[4][4];
    #pragma unroll
    for (int nt = 0; nt < 4; ++nt) {
        f32x4 bb = *(const f32x4*)&b2[nt * 16 + (l4 << 2)];
        #pragma unroll
        for (int cg = 0; cg < 4; ++cg) o[cg][nt] = bb;
    }
    #pragma unroll
    for (int kt = 0; kt < 8; ++kt) {
        #pragma unroll
        for (int nt = 0; nt < 4; ++nt) {
            h16x4 aw = ldp16(w2, kt * 4 + nt, lane);
            #pragma unroll
            for (int cg = 0; cg < 4; ++cg) o[cg][nt] = mfma16(aw, mb[cg][kt], o[cg][nt]);
        }
    }

    __syncthreads();   // barrier 2: all waves' sA reads (conv halo + residual) done

    // ---- residual + LN + clip -> ps regs + write into dead sA (wave-private rows)
    h16x4 ps[4][4];
    #pragma unroll
    for (int cg = 0; cg < 4; ++cg) {
        float v[4][4];
        float s = 0.f;
        #pragma unroll
        for (int nt = 0; nt < 4; ++nt) {
            #pragma unroll
            for (int j = 0; j < 4; ++j) {
                v[nt][j] = o[cg][nt][j] + (float)res[cg][nt][j];
                s += v[nt][j];
            }
        }
        s += __shfl_xor(s, 16); s += __shfl_xor(s, 32);
        float mu = s * (1.0f / 64.0f);
        float q = 0.f;
        #pragma unroll
        for (int nt = 0; nt < 4; ++nt) {
            #pragma unroll
            for (int j = 0; j < 4; ++j) { v[nt][j] -= mu; q += v[nt][j] * v[nt][j]; }
        }
        q += __shfl_xor(q, 16); q += __shfl_xor(q, 32);
        float rs = rsqrtf(q * (1.0f / 64.0f) + 1e-5f);
        int ri = 2 + XW + cg * 16 + l15;
        #pragma unroll
        for (int nt = 0; nt < 4; ++nt) {
            f32x4 gg = *(const f32x4*)&g[nt * 16 + (l4 << 2)];
            f32x4 bb = *(const f32x4*)&bt[nt * 16 + (l4 << 2)];
            #pragma unroll
            for (int j = 0; j < 4; ++j) {
                float ov = v[nt][j] * rs * gg[j] + bb[j];
                ov = fminf(10.0f, fmaxf(-10.0f, ov));
                ps[cg][nt][j] = (_Float16)ov;
            }
            *(h16x4*)lp(sA, ri, nt * 32 + (l4 << 3), 128) = ps[cg][nt];
        }
    }

    // ---- copy-out: full 128B lines, wave-private rows [XW, XW+64)
    {
        _Float16* dst = pout + ((size_t)b * PROW + 2 + x0 + XW) * H_;
        int lr = lane >> 3, c8 = lane & 7;        // 8 rows x 8 chunks per iter
        #pragma unroll
        for (int it = 0; it < 8; ++it) {
            int r = it * 8 + lr;                  // row within wave slab [0,64)
            h16x8 v = *(const h16x8*)lp(sA, 2 + XW + r, c8 * 16, 128);
            *(h16x8*)(dst + r * H_ + c8 * 8) = v;
        }
    }

    // ---- fused decoder head (depth 2 only; fp32 gelu — feeds y directly)
    if (yout) {
        f32x4 dacc[4][4];
        #pragma unroll
        for (int ht = 0; ht < 4; ++ht) {
            f32x4 bb = *(const f32x4*)&b1d[ht * 16 + (l4 << 2)];
            #pragma unroll
            for (int cg = 0; cg < 4; ++cg) dacc[cg][ht] = bb;
        }
        #pragma unroll
        for (int kt = 0; kt < 4; ++kt) {
            #pragma unroll
            for (int ht = 0; ht < 4; ++ht) {
                h16x4 aw = ldp16(d1, kt * 4 + ht, lane);
                #pragma unroll
                for (int cg = 0; cg < 4; ++cg) dacc[cg][ht] = mfma16(aw, ps[cg][kt], dacc[cg][ht]);
            }
        }
        float y[4] = {0.f, 0.f, 0.f, 0.f};
        #pragma unroll
        for (int ht = 0; ht < 4; ++ht) {
            f32x4 wq = *(const f32x4*)&w2d[ht * 16 + (l4 << 2)];
            #pragma unroll
            for (int cg = 0; cg < 4; ++cg) {
                #pragma unroll
                for (int j = 0; j < 4; ++j) y[cg] += gelu_fast(dacc[cg][ht][j]) * wq[j];
            }
        }
        #pragma unroll
        for (int cg = 0; cg < 4; ++cg) {
            y[cg] += __shfl_xor(y[cg], 16);
            y[cg] += __shfl_xor(y[cg], 32);
        }
        if (l4 == 0) {
            size_t ybase = ((size_t)b * TOUT + step) * X_;
            #pragma unroll
            for (int cg = 0; cg < 4; ++cg)
                yout[ybase + xg0 + cg * 16] = y[cg] + b2d[0];
        }
    }
}

extern "C" void kernel_launch(void* const* d_in, const int* in_sizes, int n_in,
                              void* d_out, int out_size, void* d_ws, size_t ws_size,
                              hipStream_t stream) {
    const float* xin    = (const float*)d_in[0];
    const float* enc_w  = (const float*)d_in[1];
    const float* enc_b  = (const float*)d_in[2];
    const float* conv_w = (const float*)d_in[3];
    const float* conv_b = (const float*)d_in[4];
    const float* mlp_w1 = (const float*)d_in[5];
    const float* mlp_b1 = (const float*)d_in[6];
    const float* mlp_w2 = (const float*)d_in[7];
    const float* mlp_b2 = (const float*)d_in[8];
    const float* ln_g   = (const float*)d_in[9];
    const float* ln_b   = (const float*)d_in[10];
    const float* dec_w1 = (const float*)d_in[11];
    const float* dec_b1 = (const float*)d_in[12];
    const float* dec_w2 = (const float*)d_in[13];
    const float* dec_b2 = (const float*)d_in[14];
    float* out = (float*)d_out;

    const size_t PSI = (size_t)B_ * PROW * H_;       // fp16 elements
    _Float16* psiA = (_Float16*)d_ws;
    _Float16* psiB = psiA + PSI;
    _Float16* cwf = psiB + PSI;               // [3][40 frags][512]
    _Float16* w1f = cwf + 61440;              // [3][32 frags][256]
    _Float16* w2f = w1f + 24576;              // [3][32 frags][256]
    _Float16* d1f = w2f + 24576;              // [16 frags][256]
    (void)ws_size; (void)n_in; (void)in_sizes; (void)out_size;

    k_zero_pads<<<32, 256, 0, stream>>>(psiA, psiB);
    k_prep_conv<<<240, 256, 0, stream>>>(conv_w, cwf);
    k_pack16<<<96, 256, 0, stream>>>(mlp_w1, w1f, 8, 4, 64, 24576);
    k_pack16<<<96, 256, 0, stream>>>(mlp_w2, w2f, 4, 8, 128, 24576);
    k_pack16<<<16, 256, 0, stream>>>(dec_w1, d1f, 4, 4, 64, 4096);

    k_encoder<<<dim3(X_ / 64, B_), 256, 0, stream>>>(xin, enc_w, enc_b, psiA);

    const _Float16* cur = psiA;
    _Float16* nxt = psiB;
    for (int t = 0; t < TOUT; ++t) {
        for (int i = 0; i < DEPTH; ++i) {
            float* yout = (i == DEPTH - 1) ? out : nullptr;
            k_layer<<<dim3(X_ / TILE, B_), 256, 0, stream>>>(
                cur, nxt,
                cwf + i * 20480, conv_b + i * H_,
                w1f + i * 8192,  mlp_b1 + i * F_,
                w2f + i * 8192,  mlp_b2 + i * H_,
                ln_g + i * H_, ln_b + i * H_,
                d1f, dec_b1, dec_w2, dec_b2, yout, t);
            _Float16* tmp = (_Float16*)cur; cur = nxt; nxt = tmp;
        }
    }
}